// Round 4
// baseline (344.494 us; speedup 1.0000x reference)
//
#include <hip/hip_runtime.h>
#include <math.h>

#define D 128
#define NB 8
#define NN1 128
#define NN2 512
#define ROWS1 (NB * NN1)          // 1024
#define ROWS2 (NB * NN2)          // 4096
#define ROWS (ROWS1 + ROWS2)      // 5120
#define CAP1 96                   // max nnz graph1 (mean ~25)
#define CAP2 160                  // max nnz graph2 (mean ~51)
#define CSR_ELEMS ((size_t)ROWS1 * CAP1 + (size_t)ROWS2 * CAP2)

__device__ __forceinline__ void resolve_row(int row, int& base_row, size_t& cbase,
                                            int& N) {
    if (row < ROWS1) {
        base_row = row & ~127;
        cbase = (size_t)row * CAP1;
        N = NN1;
    } else {
        int r = row - ROWS1;
        base_row = ROWS1 + (r & ~511);
        cbase = (size_t)ROWS1 * CAP1 + (size_t)r * CAP2;
        N = NN2;
    }
}

// ------------- fused: node embed (128 thr) + CSR build (wave 0) -------------
__global__ __launch_bounds__(128) void k_csrembed(
    const float* __restrict__ h1, const float* __restrict__ h2,
    const float* __restrict__ adj1, const float* __restrict__ adj2,
    const float* __restrict__ W, float* __restrict__ g,
    unsigned short* __restrict__ csr, int* __restrict__ nnz) {
    int row = blockIdx.x;
    int t = threadIdx.x;
    const float* src = (row < ROWS1) ? h1 + (size_t)row * 54
                                     : h2 + (size_t)(row - ROWS1) * 54;
    __shared__ float xr[56];
    if (t < 54) xr[t] = src[t];
    __syncthreads();
    float a0 = 0.f, a1 = 0.f;
#pragma unroll
    for (int k = 0; k < 54; k += 2) {
        a0 += xr[k] * W[k * D + t];
        if (k + 1 < 54) a1 += xr[k + 1] * W[(k + 1) * D + t];
    }
    g[(size_t)row * D + t] = a0 + a1;

    if (t < 64) {
        int base_row, N;
        size_t cbase;
        resolve_row(row, base_row, cbase, N);
        int cap = (row < ROWS1) ? CAP1 : CAP2;
        const float* arow = (row < ROWS1)
                                ? adj1 + (size_t)row * NN1
                                : adj2 + (size_t)(row - ROWS1) * NN2;
        int cnt = 0;
        for (int c0 = 0; c0 < N; c0 += 64) {
            float v = arow[c0 + t];
            unsigned long long m = __ballot(v > 0.f);
            int rank = __popcll(m & ((1ull << t) - 1ull));
            if (v > 0.f && cnt + rank < cap)
                csr[cbase + cnt + rank] = (unsigned short)(c0 + t);
            cnt += __popcll(m);
        }
        if (t == 0) nnz[row] = cnt < cap ? cnt : cap;
    }
}

// ---------------- h = g@W + b ; hA = h@A  (16 rows / block) ----------------
__global__ __launch_bounds__(256) void k_h(const float* __restrict__ g,
                                           const float* __restrict__ W,
                                           const float* __restrict__ bias,
                                           const float* __restrict__ A,
                                           float* __restrict__ h, float* __restrict__ hA) {
    int row0 = blockIdx.x * 16;
    int t = threadIdx.x;
    int d = t & 127, rh = t >> 7;
    __shared__ float xs[16][D];
    __shared__ float hs[16][D];
    {
        int r = t >> 4, c = (t & 15) * 8;
        *(float4*)&xs[r][c] = *(const float4*)&g[((size_t)row0 + r) * D + c];
        *(float4*)&xs[r][c + 4] = *(const float4*)&g[((size_t)row0 + r) * D + c + 4];
    }
    __syncthreads();
    float bv = bias[d];
    float acc[8];
#pragma unroll
    for (int u = 0; u < 8; ++u) acc[u] = bv;
    for (int k0 = 0; k0 < D; k0 += 4) {
        float w0 = W[(k0 + 0) * D + d];
        float w1 = W[(k0 + 1) * D + d];
        float w2 = W[(k0 + 2) * D + d];
        float w3 = W[(k0 + 3) * D + d];
#pragma unroll
        for (int u = 0; u < 8; ++u) {
            float4 xv = *(const float4*)&xs[rh * 8 + u][k0];
            acc[u] += xv.x * w0 + xv.y * w1 + xv.z * w2 + xv.w * w3;
        }
    }
#pragma unroll
    for (int u = 0; u < 8; ++u) {
        int r = rh * 8 + u;
        h[((size_t)row0 + r) * D + d] = acc[u];
        hs[r][d] = acc[u];
    }
    __syncthreads();
    float acc2[8];
#pragma unroll
    for (int u = 0; u < 8; ++u) acc2[u] = 0.f;
    for (int k0 = 0; k0 < D; k0 += 4) {
        float w0 = A[(k0 + 0) * D + d];
        float w1 = A[(k0 + 1) * D + d];
        float w2 = A[(k0 + 2) * D + d];
        float w3 = A[(k0 + 3) * D + d];
#pragma unroll
        for (int u = 0; u < 8; ++u) {
            float4 xv = *(const float4*)&hs[rh * 8 + u][k0];
            acc2[u] += xv.x * w0 + xv.y * w1 + xv.z * w2 + xv.w * w3;
        }
    }
#pragma unroll
    for (int u = 0; u < 8; ++u)
        hA[((size_t)row0 + rh * 8 + u) * D + d] = acc2[u];
}

// ---- sparse S row + softmax stats: sval[i,s] = hA[i].h[j] + h[i].hA[j] ----
// block = row; 128 thr = 16 groups x 8 lanes; each group one neighbor,
// each lane a 16-float slice -> 16 neighbors in flight per iteration.
__global__ __launch_bounds__(128) void k_Ssp(const float* __restrict__ h,
                                             const float* __restrict__ hA,
                                             const unsigned short* __restrict__ csr,
                                             const int* __restrict__ nnz,
                                             float* __restrict__ svals,
                                             float2* __restrict__ rowstat) {
    int row = blockIdx.x;
    int t = threadIdx.x;
    int base_row, N;
    size_t cbase;
    resolve_row(row, base_row, cbase, N);
    int n = nnz[row];
    int grp = t >> 3, u = t & 7;   // 16 groups, 8 lanes; slice = u*16
    __shared__ unsigned short sidx[CAP2];
    __shared__ float sv[CAP2];
    for (int s = t; s < n; s += 128) sidx[s] = csr[cbase + s];
    const float* hrow = h + (size_t)row * D + u * 16;
    const float* hArow = hA + (size_t)row * D + u * 16;
    float4 hi[4], ai[4];
#pragma unroll
    for (int q = 0; q < 4; ++q) {
        hi[q] = *(const float4*)&hrow[q * 4];
        ai[q] = *(const float4*)&hArow[q * 4];
    }
    __syncthreads();
    for (int s0 = 0; s0 < n; s0 += 16) {
        int s = s0 + grp;
        float p = 0.f;
        if (s < n) {
            int jrow = base_row + sidx[s];
            const float* hj = h + (size_t)jrow * D + u * 16;
            const float* aj = hA + (size_t)jrow * D + u * 16;
#pragma unroll
            for (int q = 0; q < 4; ++q) {
                float4 hjv = *(const float4*)&hj[q * 4];
                float4 ajv = *(const float4*)&aj[q * 4];
                p += hi[q].x * ajv.x + hi[q].y * ajv.y + hi[q].z * ajv.z +
                     hi[q].w * ajv.w + ai[q].x * hjv.x + ai[q].y * hjv.y +
                     ai[q].z * hjv.z + ai[q].w * hjv.w;
            }
        }
        p += __shfl_xor(p, 1);
        p += __shfl_xor(p, 2);
        p += __shfl_xor(p, 4);
        if (s < n && u == 0) sv[s] = p;
    }
    __syncthreads();
    if (t < 64) {
        float m = -3.4e38f;
        for (int s = t; s < n; s += 64) m = fmaxf(m, sv[s]);
#pragma unroll
        for (int o = 32; o > 0; o >>= 1) m = fmaxf(m, __shfl_xor(m, o));
        float sum = 0.f;
        for (int s = t; s < n; s += 64) sum += expf(sv[s] - m);
#pragma unroll
        for (int o = 32; o > 0; o >>= 1) sum += __shfl_xor(sum, o);
        if (t == 0) rowstat[row] = make_float2(m, 1.f / sum);
    }
    for (int s = t; s < n; s += 128) svals[cbase + s] = sv[s];
}

// ------- h_prime via symmetry + gate; 256 thr: two halves split the list ----
__global__ __launch_bounds__(256) void k_hpgate(const float* __restrict__ hbuf,
                                                float* __restrict__ g,
                                                const float* __restrict__ svals,
                                                const float2* __restrict__ rowstat,
                                                const unsigned short* __restrict__ csr,
                                                const int* __restrict__ nnz,
                                                const float* __restrict__ gW,
                                                const float* __restrict__ gb) {
    int row = blockIdx.x;
    int t = threadIdx.x;
    int d = t & 127, half = t >> 7;
    int base_row, N;
    size_t cbase;
    resolve_row(row, base_row, cbase, N);
    int n = nnz[row];
    __shared__ float avals[CAP2];
    __shared__ int aidx[CAP2];
    __shared__ float red[256];
    for (int s = t; s < n; s += 256) {
        int jrow = base_row + csr[cbase + s];
        float2 st = rowstat[jrow];
        avals[s] = expf(svals[cbase + s] - st.x) * st.y;
        aidx[s] = jrow;
    }
    __syncthreads();
    // halves interleave in blocks of 4: half0 -> s..s+3 of each 8-block, half1 -> s+4..s+7
    float a0 = 0.f, a1 = 0.f, a2 = 0.f, a3 = 0.f;
    int s = half * 4;
    for (; s + 4 <= n; s += 8) {
        a0 += avals[s + 0] * hbuf[(size_t)aidx[s + 0] * D + d];
        a1 += avals[s + 1] * hbuf[(size_t)aidx[s + 1] * D + d];
        a2 += avals[s + 2] * hbuf[(size_t)aidx[s + 2] * D + d];
        a3 += avals[s + 3] * hbuf[(size_t)aidx[s + 3] * D + d];
    }
    for (; s < n; ++s) a0 += avals[s] * hbuf[(size_t)aidx[s] * D + d];
    red[t] = a0 + a1 + a2 + a3;
    __syncthreads();
    float hv = 0.f, xv = 0.f;
    if (t < 128) {
        hv = fmaxf(red[t] + red[t + 128], 0.f);
        xv = g[(size_t)row * D + t];
    }
    __syncthreads();
    if (t < 128) red[t] = xv * gW[t] + hv * gW[D + t];
    __syncthreads();
    for (int o = 64; o > 0; o >>= 1) {
        if (t < o) red[t] += red[t + o];
        __syncthreads();
    }
    float c = 1.f / (1.f + expf(-(red[0] + gb[0])));
    if (t < 128) g[(size_t)row * D + t] = c * xv + (1.f - c) * hv;
}

// ---------------- pair-MLP precompute: aA/aB = g @ W1{A,B} (+bias g1) ------
__global__ __launch_bounds__(256) void k_pairpre(const float* __restrict__ g,
                                                 const float* __restrict__ WA,
                                                 const float* __restrict__ WB,
                                                 const float* __restrict__ bA,
                                                 const float* __restrict__ bB,
                                                 float* __restrict__ aA,
                                                 float* __restrict__ aB) {
    int row0 = blockIdx.x * 16;
    int t = threadIdx.x;
    int d = t & 127, rh = t >> 7;
    int g2 = (row0 >= ROWS1);
    const float* WAp = g2 ? WA + D * D : WA;
    const float* WBp = g2 ? WB + D * D : WB;
    __shared__ float xs[16][D];
    {
        int r = t >> 4, c = (t & 15) * 8;
        *(float4*)&xs[r][c] = *(const float4*)&g[((size_t)row0 + r) * D + c];
        *(float4*)&xs[r][c + 4] = *(const float4*)&g[((size_t)row0 + r) * D + c + 4];
    }
    __syncthreads();
    float bvA = g2 ? 0.f : bA[d];
    float bvB = g2 ? 0.f : bB[d];
    float accA[8], accB[8];
#pragma unroll
    for (int u = 0; u < 8; ++u) { accA[u] = bvA; accB[u] = bvB; }
    for (int k0 = 0; k0 < D; k0 += 4) {
        float wa0 = WAp[(k0 + 0) * D + d], wa1 = WAp[(k0 + 1) * D + d];
        float wa2 = WAp[(k0 + 2) * D + d], wa3 = WAp[(k0 + 3) * D + d];
        float wb0 = WBp[(k0 + 0) * D + d], wb1 = WBp[(k0 + 1) * D + d];
        float wb2 = WBp[(k0 + 2) * D + d], wb3 = WBp[(k0 + 3) * D + d];
#pragma unroll
        for (int u = 0; u < 8; ++u) {
            float4 xv = *(const float4*)&xs[rh * 8 + u][k0];
            accA[u] += xv.x * wa0 + xv.y * wa1 + xv.z * wa2 + xv.w * wa3;
            accB[u] += xv.x * wb0 + xv.y * wb1 + xv.z * wb2 + xv.w * wb3;
        }
    }
#pragma unroll
    for (int u = 0; u < 8; ++u) {
        int r = rh * 8 + u;
        aA[((size_t)row0 + r) * D + d] = accA[u];
        aB[((size_t)row0 + r) * D + d] = accB[u];
    }
}

// --------- fused pair z-GEMM (relu MLP) + energies, 32x32 tiles -----------
__global__ __launch_bounds__(256) void k_pairz(
    const float* __restrict__ aA, const float* __restrict__ aB,
    const float* __restrict__ w2A, const float* __restrict__ w2B,
    const float* __restrict__ b2A, const float* __restrict__ b2B,
    const float* __restrict__ pos1, const float* __restrict__ pos2,
    const float* __restrict__ vr1, const float* __restrict__ vr2,
    const float* __restrict__ nm1, const float* __restrict__ nm2,
    const float* __restrict__ A_int, float* __restrict__ partials) {
    int b = blockIdx.y;
    int itile = blockIdx.x >> 4, jtile = blockIdx.x & 15;
    int i0 = itile * 32, j0 = jtile * 32;
    int t = threadIdx.x;
    int tx = t & 15, ty = t >> 4;
    __shared__ float A1a[32][20], A1b[32][20], A2a[32][20], A2b[32][20];
    __shared__ float w2As[128], w2Bs[128];
    __shared__ float zAs[32][33], zBs[32][33];
    if (t < 128) { w2As[t] = w2A[t]; w2Bs[t] = w2B[t]; }
    float zA[2][2] = {{0.f, 0.f}, {0.f, 0.f}};
    float zB[2][2] = {{0.f, 0.f}, {0.f, 0.f}};
    int half = t >> 7, idx = t & 127;
    int sr = idx >> 2, sc = (idx & 3) * 4;
    size_t grow = half ? (size_t)(ROWS1 + b * NN2 + j0 + sr)
                       : (size_t)(b * NN1 + i0 + sr);
    for (int hc = 0; hc < D; hc += 16) {
        __syncthreads();
        float4 va = *(const float4*)&aA[grow * D + hc + sc];
        float4 vb = *(const float4*)&aB[grow * D + hc + sc];
        if (half) { *(float4*)&A2a[sr][sc] = va; *(float4*)&A2b[sr][sc] = vb; }
        else      { *(float4*)&A1a[sr][sc] = va; *(float4*)&A1b[sr][sc] = vb; }
        __syncthreads();
#pragma unroll
        for (int hh = 0; hh < 16; hh += 4) {
            float4 wA = *(const float4*)&w2As[hc + hh];
            float4 wB = *(const float4*)&w2Bs[hc + hh];
            float4 xA0 = *(const float4*)&A1a[ty][hh];
            float4 xA1 = *(const float4*)&A1a[ty + 16][hh];
            float4 xB0 = *(const float4*)&A1b[ty][hh];
            float4 xB1 = *(const float4*)&A1b[ty + 16][hh];
            float4 yA0 = *(const float4*)&A2a[tx][hh];
            float4 yA1 = *(const float4*)&A2a[tx + 16][hh];
            float4 yB0 = *(const float4*)&A2b[tx][hh];
            float4 yB1 = *(const float4*)&A2b[tx + 16][hh];
#define RD4(xx, yy, ww) (fmaxf(xx.x + yy.x, 0.f) * ww.x + fmaxf(xx.y + yy.y, 0.f) * ww.y + \
                         fmaxf(xx.z + yy.z, 0.f) * ww.z + fmaxf(xx.w + yy.w, 0.f) * ww.w)
            zA[0][0] += RD4(xA0, yA0, wA); zA[0][1] += RD4(xA0, yA1, wA);
            zA[1][0] += RD4(xA1, yA0, wA); zA[1][1] += RD4(xA1, yA1, wA);
            zB[0][0] += RD4(xB0, yB0, wB); zB[0][1] += RD4(xB0, yB1, wB);
            zB[1][0] += RD4(xB1, yB0, wB); zB[1][1] += RD4(xB1, yB1, wB);
#undef RD4
        }
    }
#pragma unroll
    for (int u = 0; u < 2; ++u)
#pragma unroll
        for (int v = 0; v < 2; ++v) {
            zAs[ty + 16 * u][tx + 16 * v] = zA[u][v];
            zBs[ty + 16 * u][tx + 16 * v] = zB[u][v];
        }
    __syncthreads();
    int j2 = t & 31, ig = t >> 5;
    int jg = j0 + j2;
    size_t j_off = (size_t)b * NN2 + jg;
    float p2x = pos2[j_off * 3 + 0], p2y = pos2[j_off * 3 + 1], p2z = pos2[j_off * 3 + 2];
    float r2 = vr2[j_off], m2 = nm2[j_off];
    float zb2A = b2A[0], zb2B = b2B[0];
    float eV[4], e1[4], e2[4], eH[4];
#pragma unroll
    for (int ii = 0; ii < 4; ++ii) {
        int il = ig * 4 + ii;
        int iglob = i0 + il;
        size_t i_off = (size_t)b * NN1 + iglob;
        float zAv = zAs[il][j2] + zb2A;
        float zBv = zBs[il][j2] + zb2B;
        float dx = pos1[i_off * 3 + 0] - p2x;
        float dy = pos1[i_off * 3 + 1] - p2y;
        float dz = pos1[i_off * 3 + 2] - p2z;
        float dm = sqrtf(dx * dx + dy * dy + dz * dz + 1e-10f);
        if (dm < 0.5f) dm = 1e10f;
        float A_w = 1.f / (1.f + expf(-zAv));
        float B_w = tanhf(zBv) * 0.2f;
        float dm0 = vr1[i_off] + r2 + B_w;
        float dm0s = (dm0 < 1e-4f) ? 1.f : dm0;
        float rr = dm0s / dm;
        float rr2 = rr * rr;
        float rN = rr2 * rr2 * rr2;
        float evdw = fminf(rN * rN - 2.f * rN, 100.f);
        float mask = nm1[i_off] * m2;
        float Aamp = A_w * (0.0356f - 0.0178f) + 0.0178f;
        eV[ii] = Aamp * evdw * mask;
        float dmd = dm - dm0;
        size_t abase = (((size_t)b * 8) * NN1 + iglob) * NN2 + jg;
        float Ai1 = A_int[abase + (size_t)1 * NN1 * NN2];
        float Ai6 = A_int[abase + (size_t)6 * NN1 * NN2];
        float Ai7 = A_int[abase + (size_t)7 * NN1 * NN2];
        e1[ii] = fminf(fmaxf(dmd * Ai1 * (-1.f / 0.7f), 0.f), 1.f);
        e2[ii] = fminf(fmaxf(dmd * Ai7 * (-1.f / 0.7f), 0.f), 1.f);
        eH[ii] = fminf(fmaxf((1.5f - dmd) * Ai6, 0.f), 1.f);
    }
#pragma unroll
    for (int o = 16; o > 0; o >>= 1) {
#pragma unroll
        for (int ii = 0; ii < 4; ++ii) {
            eV[ii] += __shfl_xor(eV[ii], o);
            e1[ii] += __shfl_xor(e1[ii], o);
            e2[ii] += __shfl_xor(e2[ii], o);
            eH[ii] += __shfl_xor(eH[ii], o);
        }
    }
    if (j2 == 0) {
#pragma unroll
        for (int ii = 0; ii < 4; ++ii) {
            int iglob = i0 + ig * 4 + ii;
            float* pp = partials + (((size_t)b * NN1 + iglob) * 16 + jtile) * 4;
            pp[0] = eV[ii]; pp[1] = e1[ii]; pp[2] = e2[ii]; pp[3] = eH[ii];
        }
    }
}

__global__ void k_final(const float* __restrict__ partials, const float* __restrict__ rotor,
                        const float* __restrict__ duff, const float* __restrict__ hbond,
                        const float* __restrict__ hydro, const float* __restrict__ vdwc,
                        const float* __restrict__ rotc, float* __restrict__ out) {
    int b = blockIdx.x;
    int t = threadIdx.x;  // 128
    __shared__ float r[4][128];
    float v0 = 0.f, v1 = 0.f, v2 = 0.f, v3 = 0.f;
    const float* p = partials + ((size_t)b * NN1 + t) * 16 * 4;
#pragma unroll
    for (int jt = 0; jt < 16; ++jt) {
        v0 += p[jt * 4 + 0]; v1 += p[jt * 4 + 1];
        v2 += p[jt * 4 + 2]; v3 += p[jt * 4 + 3];
    }
    r[0][t] = v0; r[1][t] = v1; r[2][t] = v2; r[3][t] = v3;
    __syncthreads();
    for (int s = 64; s > 0; s >>= 1) {
        if (t < s) {
            r[0][t] += r[0][t + s];
            r[1][t] += r[1][t + s];
            r[2][t] += r[2][t + s];
            r[3][t] += r[3][t + s];
        }
        __syncthreads();
    }
    if (t == 0) {
        float hb = -hbond[0] * hbond[0];
        float hy = -hydro[0] * hydro[0];
        float Et = duff[b] * vdwc[0] * vdwc[0];
        float sc = 1.f / (1.f + rotc[0] * rotc[0] * rotor[b]);
        out[b * 5 + 0] = r[0][0] * sc;
        out[b * 5 + 1] = r[1][0] * hb * sc;
        out[b * 5 + 2] = r[2][0] * hb * sc;
        out[b * 5 + 3] = r[3][0] * hy * sc;
        out[b * 5 + 4] = Et * sc;
    }
}

extern "C" void kernel_launch(void* const* d_in, const int* in_sizes, int n_in,
                              void* d_out, int out_size, void* d_ws, size_t ws_size,
                              hipStream_t stream) {
    const float* h1    = (const float*)d_in[0];
    const float* adj1  = (const float*)d_in[1];
    const float* h2    = (const float*)d_in[2];
    const float* adj2  = (const float*)d_in[3];
    const float* A_int = (const float*)d_in[4];
    const float* pos1  = (const float*)d_in[5];
    const float* pos2  = (const float*)d_in[6];
    const float* rotor = (const float*)d_in[7];
    const float* vr1   = (const float*)d_in[8];
    const float* vr2   = (const float*)d_in[9];
    const float* duff  = (const float*)d_in[10];
    const float* nm1   = (const float*)d_in[11];
    const float* nm2   = (const float*)d_in[12];
    const float* nodeW = (const float*)d_in[13];
    const float* gatW  = (const float*)d_in[14];
    const float* gatb  = (const float*)d_in[15];
    const float* gatA  = (const float*)d_in[16];
    const float* gateW = (const float*)d_in[17];
    const float* gateb = (const float*)d_in[18];
    const float* vA_W1 = (const float*)d_in[19];
    const float* vA_b1 = (const float*)d_in[20];
    const float* vA_W2 = (const float*)d_in[21];
    const float* vA_b2 = (const float*)d_in[22];
    const float* vB_W1 = (const float*)d_in[23];
    const float* vB_b1 = (const float*)d_in[24];
    const float* vB_W2 = (const float*)d_in[25];
    const float* vB_b2 = (const float*)d_in[26];
    const float* hbond = (const float*)d_in[27];
    const float* hydro = (const float*)d_in[28];
    const float* vdwc  = (const float*)d_in[29];
    const float* rotc  = (const float*)d_in[30];

    float* p = (float*)d_ws;
    float* g     = p; p += (size_t)ROWS * D;
    float* hbuf  = p; p += (size_t)ROWS * D;
    float* hAbuf = p; p += (size_t)ROWS * D;
    float* svals = p; p += CSR_ELEMS;
    float2* rowstat = (float2*)p; p += 2 * (size_t)ROWS;
    float* partials = p; p += (size_t)NB * NN1 * 16 * 4;
    unsigned short* csr = (unsigned short*)p;
    int* nnz = (int*)(csr + CSR_ELEMS);
    float* aA = hbuf;   // aliases: hbuf/hAbuf dead after last k_hpgate
    float* aB = hAbuf;

    k_csrembed<<<ROWS, 128, 0, stream>>>(h1, h2, adj1, adj2, nodeW, g, csr, nnz);

    for (int l = 0; l < 3; ++l) {
        const float* W  = gatW  + (size_t)l * D * D;
        const float* bb = gatb  + (size_t)l * D;
        const float* A  = gatA  + (size_t)l * D * D;
        const float* gW = gateW + (size_t)l * 2 * D;
        const float* gb = gateb + l;
        k_h<<<ROWS / 16, 256, 0, stream>>>(g, W, bb, A, hbuf, hAbuf);
        k_Ssp<<<ROWS, 128, 0, stream>>>(hbuf, hAbuf, csr, nnz, svals, rowstat);
        k_hpgate<<<ROWS, 256, 0, stream>>>(hbuf, g, svals, rowstat, csr, nnz, gW, gb);
    }

    k_pairpre<<<ROWS / 16, 256, 0, stream>>>(g, vA_W1, vB_W1, vA_b1, vB_b1, aA, aB);
    k_pairz<<<dim3(64, NB), 256, 0, stream>>>(aA, aB, vA_W2, vB_W2, vA_b2, vB_b2,
                                              pos1, pos2, vr1, vr2, nm1, nm2, A_int,
                                              partials);
    k_final<<<NB, 128, 0, stream>>>(partials, rotor, duff, hbond, hydro, vdwc, rotc,
                                    (float*)d_out);
}